// Round 14
// baseline (905.512 us; speedup 1.0000x reference)
//
#include <hip/hip_runtime.h>
#include <stdint.h>

// GeneDynamics: out = -x + (A @ x^2) / (x^2 + 1)
// v10: barrier-free streaming. xh^T slice staged once in LDS (128 KiB,
//      1 block/CU); 16 waves free-run, each streaming 4 rows x 1 KiB
//      contiguous windows (8 KB runs/row). Conflict-free b128 LDS reads.
//      Per-quad 6-stage shfl butterfly merges lane partials -> atomics.

#define NN 16384
#define DIM 16
#define TPB 1024               // 16 waves
#define BROWS 512              // rows per block (32 per wave)
#define KSPLIT 8
#define KRANGE 2048            // k per block
#define NQUAD 8                // 4-row quads per wave

// prep: out = -x ; inv = 1/(x^2+1) ; xhT[d][i] = x[i][d]^2 (transposed)
__global__ __launch_bounds__(256) void prep_kernel(const float* __restrict__ x,
                                                   float* __restrict__ out,
                                                   float* __restrict__ xhT,
                                                   float* __restrict__ inv) {
    int i = blockIdx.x * 256 + threadIdx.x;           // row 0..16383
    const float4* xr = reinterpret_cast<const float4*>(x + (size_t)i * DIM);
    float4* orow = reinterpret_cast<float4*>(out + (size_t)i * DIM);
    float4* irow = reinterpret_cast<float4*>(inv + (size_t)i * DIM);
    #pragma unroll
    for (int v = 0; v < 4; ++v) {
        float4 xv = xr[v];
        orow[v] = make_float4(-xv.x, -xv.y, -xv.z, -xv.w);
        float4 h = make_float4(xv.x * xv.x, xv.y * xv.y, xv.z * xv.z, xv.w * xv.w);
        irow[v] = make_float4(1.f / (h.x + 1.f), 1.f / (h.y + 1.f),
                              1.f / (h.z + 1.f), 1.f / (h.w + 1.f));
        xhT[(size_t)(4 * v + 0) * NN + i] = h.x;      // lanes -> consecutive i: coalesced
        xhT[(size_t)(4 * v + 1) * NN + i] = h.y;
        xhT[(size_t)(4 * v + 2) * NN + i] = h.z;
        xhT[(size_t)(4 * v + 3) * NN + i] = h.w;
    }
}

__global__ __launch_bounds__(TPB, 4) void agg_kernel(const float* __restrict__ A,
                                                     const float* __restrict__ xhT,
                                                     const float* __restrict__ inv,
                                                     float* __restrict__ out) {
    __shared__ float xs[DIM * KRANGE];   // 128 KiB: xs[d*2048 + kk]

    const int tid = threadIdx.x;
    const int l = tid & 63, w = tid >> 6;
    const int ks = blockIdx.x & (KSPLIT - 1);
    const int rb = blockIdx.x >> 3;
    const int r0 = rb * BROWS;
    const int k0 = ks * KRANGE;

    // ---- one-time stage of xh^T slice (coalesced, conflict-free) ----
    #pragma unroll
    for (int p = 0; p < 8; ++p) {
        int f = p * TPB + tid;           // f4 index 0..8191
        int d = f >> 9;                  // 0..15
        int kk = (f & 511) << 2;         // 0..2044
        float4 v = *reinterpret_cast<const float4*>(xhT + (size_t)d * NN + k0 + kk);
        *reinterpret_cast<float4*>(&xs[d * KRANGE + kk]) = v;
    }
    __syncthreads();                     // ONLY barrier in the kernel

#define COMPUTE(WIN, AS)                                                \
    {                                                                   \
        _Pragma("unroll")                                               \
        for (int d = 0; d < 16; ++d) {                                  \
            float4 xq = *reinterpret_cast<const float4*>(               \
                &xs[d * KRANGE + (WIN) * 256 + 4 * l]);                 \
            _Pragma("unroll")                                           \
            for (int j = 0; j < 4; ++j)                                 \
                acc[j * 16 + d] += AS[j].x * xq.x + AS[j].y * xq.y +    \
                                   AS[j].z * xq.z + AS[j].w * xq.w;     \
        }                                                               \
    }

    const float* Aw = A + (size_t)(r0 + w * 32) * NN + k0 + 4 * l;
    const int myb5 = (l >> 5) & 1, myb4 = (l >> 4) & 1, myb3 = (l >> 3) & 1,
              myb2 = (l >> 2) & 1, myb1 = (l >> 1) & 1, myb0 = l & 1;

    for (int quad = 0; quad < NQUAD; ++quad) {
        float acc[64];
        #pragma unroll
        for (int i = 0; i < 64; ++i) acc[i] = 0.f;

        const float* Aq = Aw + (size_t)(quad * 4) * NN;
        float4 aA[4], aB[4];
        #pragma unroll
        for (int j = 0; j < 4; ++j)
            aA[j] = *reinterpret_cast<const float4*>(Aq + (size_t)j * NN);

        #pragma unroll
        for (int wp = 0; wp < 4; ++wp) {
            // prefetch window 2wp+1 while computing 2wp
            #pragma unroll
            for (int j = 0; j < 4; ++j)
                aB[j] = *reinterpret_cast<const float4*>(
                    Aq + (size_t)j * NN + (2 * wp + 1) * 256);
            COMPUTE(2 * wp, aA);
            if (wp < 3) {
                #pragma unroll
                for (int j = 0; j < 4; ++j)
                    aA[j] = *reinterpret_cast<const float4*>(
                        Aq + (size_t)j * NN + (2 * wp + 2) * 256);
            }
            COMPUTE(2 * wp + 1, aB);
        }

        // ---- 6-stage butterfly: lane l ends with output idx l (row l>>4, dim l&15) ----
        #pragma unroll
        for (int i = 0; i < 32; ++i) {
            float send = myb5 ? acc[i] : acc[i + 32];
            float keep = myb5 ? acc[i + 32] : acc[i];
            acc[i] = keep + __shfl_xor(send, 32);
        }
        #pragma unroll
        for (int i = 0; i < 16; ++i) {
            float send = myb4 ? acc[i] : acc[i + 16];
            float keep = myb4 ? acc[i + 16] : acc[i];
            acc[i] = keep + __shfl_xor(send, 16);
        }
        #pragma unroll
        for (int i = 0; i < 8; ++i) {
            float send = myb3 ? acc[i] : acc[i + 8];
            float keep = myb3 ? acc[i + 8] : acc[i];
            acc[i] = keep + __shfl_xor(send, 8);
        }
        #pragma unroll
        for (int i = 0; i < 4; ++i) {
            float send = myb2 ? acc[i] : acc[i + 4];
            float keep = myb2 ? acc[i + 4] : acc[i];
            acc[i] = keep + __shfl_xor(send, 4);
        }
        #pragma unroll
        for (int i = 0; i < 2; ++i) {
            float send = myb1 ? acc[i] : acc[i + 2];
            float keep = myb1 ? acc[i + 2] : acc[i];
            acc[i] = keep + __shfl_xor(send, 2);
        }
        {
            float send = myb0 ? acc[0] : acc[1];
            float keep = myb0 ? acc[1] : acc[0];
            acc[0] = keep + __shfl_xor(send, 1);
        }

        // ---- epilogue: out[R][d] += partial * inv[R][d]  (split-K exact) ----
        const int R = r0 + w * 32 + quad * 4 + (l >> 4);
        const int d = l & 15;
        float val = acc[0] * inv[(size_t)R * DIM + d];
        atomicAdd(out + (size_t)R * DIM + d, val);
    }
#undef COMPUTE
}

extern "C" void kernel_launch(void* const* d_in, const int* in_sizes, int n_in,
                              void* d_out, int out_size, void* d_ws, size_t ws_size,
                              hipStream_t stream) {
    const float* A = (const float*)d_in[0];
    const float* x = (const float*)d_in[1];
    float* out = (float*)d_out;
    float* xhT = (float*)d_ws;                      // 1 MiB  [16][16384]
    float* inv = (float*)d_ws + (size_t)NN * DIM;   // 1 MiB  [16384][16]

    prep_kernel<<<NN / 256, 256, 0, stream>>>(x, out, xhT, inv);
    agg_kernel<<<(NN / BROWS) * KSPLIT, TPB, 0, stream>>>(A, xhT, inv, out);
}